// Round 10
// baseline (211.646 us; speedup 1.0000x reference)
//
#include <hip/hip_runtime.h>
#include <math.h>

#define DIM   1024
#define NH    16
#define HD    64
#define GRP   128
#define BB    2
#define TT    2048
#define MROWS (BB*TT)   // 4096

typedef __attribute__((ext_vector_type(8))) short s16x8;
typedef __attribute__((ext_vector_type(4))) float f32x4;
typedef __attribute__((ext_vector_type(16))) float f32x16;
typedef __attribute__((ext_vector_type(4))) int   i32x4;
typedef __attribute__((ext_vector_type(16))) int  i32x16;
typedef __attribute__((ext_vector_type(2))) unsigned u32x2;

__device__ inline float wave_max(float v){
    for(int off=32; off; off>>=1) v = fmaxf(v, __shfl_xor(v, off));
    return v;
}

__device__ inline unsigned short f2bf(float x){
    union { float f; unsigned u; } v; v.f = x;
    unsigned r = v.u + 0x7fffu + ((v.u >> 16) & 1u);
    return (unsigned short)(r >> 16);
}

#if __has_builtin(__builtin_amdgcn_cvt_pk_bf16_f32)
typedef __bf16 bf16x2 __attribute__((ext_vector_type(2)));
__device__ inline unsigned pk2(float a, float b){
    union { bf16x2 v; unsigned u; } c;
    c.v = __builtin_amdgcn_cvt_pk_bf16_f32(a, b);
    return c.u;
}
#else
__device__ inline unsigned pk2(float a, float b){
    return (unsigned)f2bf(a) | ((unsigned)f2bf(b) << 16);
}
#endif

#if __has_builtin(__builtin_amdgcn_exp2f)
__device__ inline float fexp2(float x){ return __builtin_amdgcn_exp2f(x); }
#else
__device__ inline float fexp2(float x){ return exp2f(x); }
#endif

__device__ inline float m3(float a, float b, float c){ return fmaxf(fmaxf(a,b), c); }

// lswap(a,b) -> lo, hi via one v_permlane32_swap_b32 (VALU, no DS).
__device__ inline void lswap(unsigned a, unsigned b, unsigned &lo, unsigned &hi){
#if __has_builtin(__builtin_amdgcn_permlane32_swap)
    u32x2 r = __builtin_amdgcn_permlane32_swap(a, b, false, false);
    lo = r[0]; hi = r[1];
#else
    bool h = (threadIdx.x & 32) != 0;
    unsigned sa = (unsigned)__shfl_xor((int)a, 32);
    unsigned sb = (unsigned)__shfl_xor((int)b, 32);
    lo = h ? sb : a;
    hi = h ? b : sa;
#endif
}

__device__ inline float pairmax(float x){
    union { float f; unsigned u; } a, lo, hi;
    a.f = x;
    lswap(a.u, a.u, lo.u, hi.u);
    return fmaxf(lo.f, hi.f);
}
__device__ inline float pairsum(float x){
    union { float f; unsigned u; } a, lo, hi;
    a.f = x;
    lswap(a.u, a.u, lo.u, hi.u);
    return lo.f + hi.f;
}

__device__ inline i32x16 zero16(){
    i32x16 z;
    #pragma unroll
    for(int i=0;i<16;i++) z[i]=0;
    return z;
}

#define QSC 0.18033688011112042f   // 0.125 * log2(e)

// int8 fragment order (GEMMs): for 32-row block rb, entry ((g*4+s)*64+lane)*16
// holds rows[lane&31], k = g*128 + (s*2 + (lane>>5))*16 .. +15.
//
// bf16 32x32 A-fragment order (attn K): per bh, 32-key tile kt, s in [0,4):
//   byte addr = bh*262144 + kt*4096 + s*1024 + lane*16
//   contents  = K[t = kt*32 + (lane&31)][d = s*16 + (lane>>5)*8 + 0..7]
// bf16 V^T A-fragment order (attn V): per bh, tile kt, hv,ks in {0,1}:
//   byte addr = bh*262144 + kt*4096 + (hv*2+ks)*1024 + lane*16
//   contents  = V[t = kt*32 + ks*16 + (lane>>5)*8 + 0..7][d = 32*hv + (lane&31)]

// ---------------- fused quantization -> fragment-order int8 ----------------
__global__ __launch_bounds__(256) void quant_all(const float* __restrict__ x,
                                                 const float* __restrict__ w0,
                                                 const float* __restrict__ w1,
                                                 const float* __restrict__ w2,
                                                 const float* __restrict__ w3,
                                                 char* __restrict__ wpk,
                                                 float* __restrict__ wsall,
                                                 char* __restrict__ xpk,
                                                 float* __restrict__ srow){
    int blk = blockIdx.x;
    int tid = threadIdx.x;
    if (blk < 1024){
        int widx = blk >> 8;
        const float* w = (widx==0)?w0 : (widx==1)?w1 : (widx==2)?w2 : w3;
        int gloc = (blk & 255)*32 + (tid >> 3);   // group index = n*8 + g
        int j = tid & 7;
        const float* p = w + (size_t)gloc*GRP;
        // contiguous 64B chunk per thread, values kept in regs for the quant pass
        float4 vv[4];
        float r = 0.f;
        #pragma unroll
        for(int c4=0;c4<4;c4++){
            vv[c4] = *(const float4*)(p + j*16 + c4*4);
            r += (fabsf(vv[c4].x)+fabsf(vv[c4].y)) + (fabsf(vv[c4].z)+fabsf(vv[c4].w));
        }
        r += __shfl_xor(r, 1);
        r += __shfl_xor(r, 2);
        r += __shfl_xor(r, 4);
        float ws = r/(float)GRP + 1e-5f;
        if (j == 0) wsall[widx*8192 + gloc] = ws;
        float rws = 1.f/ws;       // one divide instead of 64
        int n = gloc >> 3, g = gloc & 7;
        char* base = wpk + (size_t)widx*1048576 + (size_t)(n>>5)*32768
                   + (size_t)(((g*4 + (j>>1))*64 + ((j&1)*32 + (n&31)))*16);
        #pragma unroll
        for(int c4=0;c4<4;c4++){
            float4 v = vv[c4];
            int b0 = (int)fminf(fmaxf(rintf(v.x*rws),-1.f),1.f);
            int b1 = (int)fminf(fmaxf(rintf(v.y*rws),-1.f),1.f);
            int b2 = (int)fminf(fmaxf(rintf(v.z*rws),-1.f),1.f);
            int b3 = (int)fminf(fmaxf(rintf(v.w*rws),-1.f),1.f);
            *(int*)(base + c4*4) = (b0&0xff) | ((b1&0xff)<<8) | ((b2&0xff)<<16) | ((b3&0xff)<<24);
        }
    } else {
        int row = blk - 1024;
        const float* p = x + (size_t)row*DIM;
        float4 v = *(const float4*)(p + tid*4);
        float m = fmaxf(fmaxf(fabsf(v.x),fabsf(v.y)), fmaxf(fabsf(v.z),fabsf(v.w)));
        m = wave_max(m);
        __shared__ float red[4];
        if ((tid&63)==0) red[tid>>6] = m;
        __syncthreads();
        m = fmaxf(fmaxf(red[0],red[1]), fmaxf(red[2],red[3]));
        float s = 127.f/(m+1e-5f);
        int a0 = (int)fminf(fmaxf(rintf(v.x*s),-128.f),127.f);
        int a1 = (int)fminf(fmaxf(rintf(v.y*s),-128.f),127.f);
        int a2 = (int)fminf(fmaxf(rintf(v.z*s),-128.f),127.f);
        int a3 = (int)fminf(fmaxf(rintf(v.w*s),-128.f),127.f);
        int pk = (a0&0xff) | ((a1&0xff)<<8) | ((a2&0xff)<<16) | ((a3&0xff)<<24);
        int g = tid >> 5, chunk = (tid&31) >> 2;
        *(int*)(xpk + (size_t)(row>>5)*32768
               + (size_t)(((g*4 + (chunk>>1))*64 + ((chunk&1)*32 + (row&31)))*16)
               + (tid&3)*4) = pk;
        if (tid==0) srow[row] = s;
    }
}

// ---------------- activation quantization -> fragment-order (attn output) ----------------
__global__ __launch_bounds__(256) void quant_x_i8(const float* __restrict__ x,
                                                  char* __restrict__ xpk,
                                                  float* __restrict__ srow){
    int row = blockIdx.x;
    int tid = threadIdx.x;
    const float* p = x + (size_t)row*DIM;
    float4 v = *(const float4*)(p + tid*4);
    float m = fmaxf(fmaxf(fabsf(v.x),fabsf(v.y)), fmaxf(fabsf(v.z),fabsf(v.w)));
    m = wave_max(m);
    __shared__ float red[4];
    if ((tid&63)==0) red[tid>>6] = m;
    __syncthreads();
    m = fmaxf(fmaxf(red[0],red[1]), fmaxf(red[2],red[3]));
    float s = 127.f/(m+1e-5f);
    int a0 = (int)fminf(fmaxf(rintf(v.x*s),-128.f),127.f);
    int a1 = (int)fminf(fmaxf(rintf(v.y*s),-128.f),127.f);
    int a2 = (int)fminf(fmaxf(rintf(v.z*s),-128.f),127.f);
    int a3 = (int)fminf(fmaxf(rintf(v.w*s),-128.f),127.f);
    int pk = (a0&0xff) | ((a1&0xff)<<8) | ((a2&0xff)<<16) | ((a3&0xff)<<24);
    int g = tid >> 5, chunk = (tid&31) >> 2;
    *(int*)(xpk + (size_t)(row>>5)*32768
           + (size_t)(((g*4 + (chunk>>1))*64 + ((chunk&1)*32 + (row&31)))*16)
           + (tid&3)*4) = pk;
    if (tid==0) srow[row] = s;
}

// ---------------- barrier-free int8 MFMA K-loops on fragment-order operands ----------------
// 32x128-per-wave variant (gemm_i8; keeps 2 waves/SIMD TLP for the small GEMM)
__device__ inline void kloop_pk(const char* __restrict__ A,
                                const char* __restrict__ B0,
                                const char* __restrict__ B1,
                                const float wsr[2][8],
                                float facc[2][16]){
    int lane = threadIdx.x & 63;
    #pragma unroll
    for(int g=0; g<8; g++){
        i32x16 iacc[2];
        iacc[0]=zero16(); iacc[1]=zero16();
        #pragma unroll
        for(int s=0; s<4; s++){
            size_t off = (size_t)(((g*4+s)*64 + lane)*16);
            i32x4 afr = *(const i32x4*)(A  + off);
            i32x4 b0  = *(const i32x4*)(B0 + off);
            i32x4 b1  = *(const i32x4*)(B1 + off);
            iacc[0] = __builtin_amdgcn_mfma_i32_32x32x32_i8(afr, b0, iacc[0], 0, 0, 0);
            iacc[1] = __builtin_amdgcn_mfma_i32_32x32x32_i8(afr, b1, iacc[1], 0, 0, 0);
        }
        #pragma unroll
        for(int jt=0; jt<2; jt++)
            #pragma unroll
            for(int r=0;r<16;r++)
                facc[jt][r] += (float)iacc[jt][r] * wsr[jt][g];
    }
}

// 64x64-per-wave variant (gemm_qkv): square wave tile -> 1.0 KB loaded per
// MFMA vs 1.5 for 32x128. Kernel-wide load traffic -33%.
__device__ inline void kloop64(const char* __restrict__ A0,
                               const char* __restrict__ B0,
                               const float wsr[2][8],
                               float facc[2][2][16]){
    int lane = threadIdx.x & 63;
    const char* A1 = A0 + 32768;
    const char* B1 = B0 + 32768;
    #pragma unroll
    for(int g=0; g<8; g++){
        i32x16 i00=zero16(), i01=zero16(), i10=zero16(), i11=zero16();
        #pragma unroll
        for(int s=0; s<4; s++){
            size_t off = (size_t)(((g*4+s)*64 + lane)*16);
            i32x4 a0 = *(const i32x4*)(A0 + off);
            i32x4 a1 = *(const i32x4*)(A1 + off);
            i32x4 b0 = *(const i32x4*)(B0 + off);
            i32x4 b1 = *(const i32x4*)(B1 + off);
            i00 = __builtin_amdgcn_mfma_i32_32x32x32_i8(a0, b0, i00, 0, 0, 0);
            i01 = __builtin_amdgcn_mfma_i32_32x32x32_i8(a0, b1, i01, 0, 0, 0);
            i10 = __builtin_amdgcn_mfma_i32_32x32x32_i8(a1, b0, i10, 0, 0, 0);
            i11 = __builtin_amdgcn_mfma_i32_32x32x32_i8(a1, b1, i11, 0, 0, 0);
        }
        #pragma unroll
        for(int r=0;r<16;r++){
            facc[0][0][r] += (float)i00[r] * wsr[0][g];
            facc[0][1][r] += (float)i01[r] * wsr[1][g];
            facc[1][0][r] += (float)i10[r] * wsr[0][g];
            facc[1][1][r] += (float)i11[r] * wsr[1][g];
        }
    }
}

// ---------------- fused QKV int8 GEMM + RoPE/bf16 pack epilogue ----------------
// grid (24, 64), 128 threads: 2 waves, each computing 64x64 (kloop64).
__global__ __launch_bounds__(128, 2) void gemm_qkv(const char* __restrict__ Apk,
                                                   const char* __restrict__ wpk,
                                                   const float* __restrict__ wsall,
                                                   const float* __restrict__ srow,
                                                   const float* __restrict__ cosb,
                                                   const float* __restrict__ sinb,
                                                   unsigned short* __restrict__ Qh,
                                                   unsigned short* __restrict__ Kf,
                                                   unsigned short* __restrict__ Vf){
    __shared__ float T[64*132];   // 33792 B, epilogue only

    int nt = blockIdx.x;
    int widx = nt >> 3;
    int n0 = (nt & 7)*128;
    int m0 = blockIdx.y*64;
    const char* W = wpk + (size_t)widx*1048576;
    const float* wsb = wsall + widx*8192;

    int tid = threadIdx.x;
    int w = tid >> 6, lane = tid & 63;   // w: column half (64 cols per wave)
    int l31 = lane & 31, lh = lane >> 5;

    float wsr[2][8];
    #pragma unroll
    for(int ci=0; ci<2; ci++){
        int col = n0 + w*64 + ci*32 + l31;
        float4 q0 = *(const float4*)(wsb + (size_t)col*8);
        float4 q1 = *(const float4*)(wsb + (size_t)col*8 + 4);
        wsr[ci][0]=q0.x; wsr[ci][1]=q0.y; wsr[ci][2]=q0.z; wsr[ci][3]=q0.w;
        wsr[ci][4]=q1.x; wsr[ci][5]=q1.y; wsr[ci][6]=q1.z; wsr[ci][7]=q1.w;
    }

    float facc[2][2][16];
    #pragma unroll
    for(int ri=0;ri<2;ri++)
        #pragma unroll
        for(int ci=0;ci<2;ci++)
            #pragma unroll
            for(int r=0;r<16;r++) facc[ri][ci][r]=0.f;

    const char* A0 = Apk + (size_t)(m0>>5)*32768;
    const char* B0 = W   + (size_t)((n0>>5) + w*2)*32768;
    kloop64(A0, B0, wsr, facc);

    // ---- dequant into LDS fp32 tile ----
    #pragma unroll
    for(int ri=0; ri<2; ri++)
        #pragma unroll
        for(int r=0; r<16; r++){
            int rowl = ri*32 + (r&3) + 8*(r>>2) + 4*lh;
            float rsv = 1.f / srow[m0 + rowl];
            #pragma unroll
            for(int ci=0; ci<2; ci++)
                T[rowl*132 + w*64 + ci*32 + l31] = facc[ri][ci][r] * rsv;
        }
    __syncthreads();

    int bglob = m0 >> 11;            // batch, block-uniform
    int h0 = n0 >> 6;                // first of the 2 heads this block covers
    int kt0 = (m0 & (TT-1)) >> 5;    // first 32-key tile this block covers

    if (widx == 0){
        // ---- Q: row-order bf16, RoPE + QSC ----
        #pragma unroll
        for(int i=0;i<2;i++){
            int e = tid + 128*i;
            int row = e & 63, chunk = e >> 6;
            int t = (m0 + row) & (TT-1);
            const float* Tr = T + row*132 + chunk*32;
            int colbase = n0 + chunk*32;
            int h = colbase >> 6;
            int d0 = colbase & 63;
            int bh = bglob*NH + h;
            unsigned short* dst = Qh + ((size_t)bh*TT + t)*HD + d0;
            int p0 = d0 >> 1;
            __align__(16) unsigned short ob[32];
            #pragma unroll
            for(int pp=0; pp<16; pp++){
                float c = cosb[t*32 + p0 + pp], s = sinb[t*32 + p0 + pp];
                float ev = Tr[2*pp], ov = Tr[2*pp+1];
                ob[2*pp]   = f2bf((ev*c - ov*s)*QSC);
                ob[2*pp+1] = f2bf((ev*s + ov*c)*QSC);
            }
            #pragma unroll
            for(int c4=0;c4<4;c4++)
                *(s16x8*)(dst + c4*8) = *(s16x8*)(ob + c4*8);
        }
    } else if (widx == 1){
        // ---- K: 32x32 A-fragment order bf16, RoPE ----
        #pragma unroll
        for(int i=0;i<8;i++){
            int e = tid + 128*i;
            int hh = e >> 9, ktl = (e >> 8)&1, s = (e >> 6)&3;
            int ln = e & 63, li = ln & 31, hi2 = ln >> 5;
            int row = ktl*32 + li;
            int t = (m0 + row) & (TT-1);
            int d0 = s*16 + hi2*8;
            const float* Tr = T + row*132 + hh*64 + d0;
            int p0 = d0 >> 1;
            __align__(16) unsigned short ob[8];
            #pragma unroll
            for(int pp=0;pp<4;pp++){
                float c = cosb[t*32 + p0 + pp], sn = sinb[t*32 + p0 + pp];
                float ev = Tr[2*pp], ov = Tr[2*pp+1];
                ob[2*pp]   = f2bf(ev*c - ov*sn);
                ob[2*pp+1] = f2bf(ev*sn + ov*c);
            }
            int bh = bglob*NH + h0 + hh;
            size_t dst = (size_t)bh*262144 + (size_t)(((kt0 + ktl)*4 + s)*64 + ln)*16;
            *(s16x8*)((char*)Kf + dst) = *(s16x8*)ob;
        }
    } else {
        // ---- V: V^T A-fragment order bf16 ----
        #pragma unroll
        for(int i=0;i<8;i++){
            int e = tid + 128*i;
            int hh = e >> 9, ktl = (e >> 8)&1, hv = (e >> 7)&1, ks = (e >> 6)&1;
            int ln = e & 63, li = ln & 31, hi2 = ln >> 5;
            int tl0 = ktl*32 + ks*16 + hi2*8;
            int col = hh*64 + 32*hv + li;
            __align__(16) unsigned short ob[8];
            #pragma unroll
            for(int jj=0;jj<8;jj++)
                ob[jj] = f2bf(T[(tl0+jj)*132 + col]);
            int bh = bglob*NH + h0 + hh;
            size_t dst = (size_t)bh*262144 + (size_t)((((kt0 + ktl)*2 + hv)*2 + ks)*64 + ln)*16;
            *(s16x8*)((char*)Vf + dst) = *(s16x8*)ob;
        }
    }
}

// ---------------- barrier-free int8 MFMA GEMM (output projection) ----------------
__global__ __launch_bounds__(256) void gemm_i8(const char* __restrict__ Apk,
                                               const char* __restrict__ Wp,
                                               const float* __restrict__ wsb,
                                               const float* __restrict__ srow,
                                               float* __restrict__ C){
    int tid = threadIdx.x;
    int w = tid >> 6, lane = tid & 63;
    int wm = w & 1, wn = w >> 1;
    int m0 = blockIdx.y*64, n0 = blockIdx.x*128;
    int l31 = lane & 31, lh = lane >> 5;

    float wsr[2][8];
    #pragma unroll
    for(int jt=0; jt<2; jt++){
        int col = n0 + (wn*2+jt)*32 + l31;
        float4 q0 = *(const float4*)(wsb + (size_t)col*8);
        float4 q1 = *(const float4*)(wsb + (size_t)col*8 + 4);
        wsr[jt][0]=q0.x; wsr[jt][1]=q0.y; wsr[jt][2]=q0.z; wsr[jt][3]=q0.w;
        wsr[jt][4]=q1.x; wsr[jt][5]=q1.y; wsr[jt][6]=q1.z; wsr[jt][7]=q1.w;
    }

    float facc[2][16];
    #pragma unroll
    for(int b=0;b<2;b++)
        #pragma unroll
        for(int r=0;r<16;r++) facc[b][r]=0.f;

    const char* A  = Apk + (size_t)((m0>>5) + wm)*32768;
    const char* B0 = Wp  + (size_t)((n0>>5) + wn*2)*32768;
    const char* B1 = B0 + 32768;
    kloop_pk(A, B0, B1, wsr, facc);

    #pragma unroll
    for(int r=0; r<16; r++){
        int rowl = wm*32 + (r&3) + 8*(r>>2) + 4*lh;
        float rsv = 1.f / srow[m0 + rowl];
        #pragma unroll
        for(int jt=0; jt<2; jt++){
            int col = n0 + (wn*2+jt)*32 + l31;
            C[(size_t)(m0+rowl)*DIM + col] = facc[jt][r] * rsv;
        }
    }
}

// ---------------- MFMA flash attention v11: 3 blocks/CU via V-single-buffer ----------------
// v9 math/structure, but V is loaded at the top of its own tile (first use,
// PV, is ~400cy later -> L2 latency still hidden) instead of a tile ahead.
// Saves 16 VGPRs -> peak live ~132 -> fits __launch_bounds__(256,3)'s
// 170-VGPR budget: 3 blocks/CU (12 waves/CU), +50% TLP over v9's 2 blocks.
__device__ __attribute__((always_inline)) inline
void loadK(const char* __restrict__ Kp, int kt, int laneoff, s16x8 kc[4]){
    const char* kb = Kp + (size_t)kt*4096 + laneoff;
    #pragma unroll
    for(int s=0;s<4;s++) kc[s] = *(const s16x8*)(kb + s*1024);
}
__device__ __attribute__((always_inline)) inline
void loadV(const char* __restrict__ Vp, int kt, int laneoff, s16x8 vf[4]){
    const char* vb = Vp + (size_t)kt*4096 + laneoff;
    #pragma unroll
    for(int i=0;i<4;i++) vf[i] = *(const s16x8*)(vb + i*1024);
}

__device__ __attribute__((always_inline)) inline
void tile_compute(const s16x8 kc[4], const s16x8 vf[4], int kt, int j,
                  int hi, int q, const s16x8 Qf[4],
                  f32x16& Of0, f32x16& Of1, float& mrow, float& lrow){
    f32x16 S;
    #pragma unroll
    for(int r=0;r<16;r++) S[r]=0.f;
    __builtin_amdgcn_s_setprio(1);
    #pragma unroll
    for(int s=0;s<4;s++)
        S = __builtin_amdgcn_mfma_f32_32x32x16_bf16(kc[s], Qf[s], S, 0, 0, 0);
    __builtin_amdgcn_s_setprio(0);

    float p[16];
    if (kt == j){
        #pragma unroll
        for(int r=0;r<16;r++){
            int key = kt*32 + (r&3) + 8*(r>>2) + 4*hi;
            p[r] = (key > q) ? -1e30f : S[r];
        }
    } else {
        #pragma unroll
        for(int r=0;r<16;r++) p[r] = S[r];
    }

    float a0=m3(p[0],p[1],p[2]), a1=m3(p[3],p[4],p[5]), a2=m3(p[6],p[7],p[8]),
          a3=m3(p[9],p[10],p[11]), a4=m3(p[12],p[13],p[14]);
    float mloc = pairmax(fmaxf(m3(a0,a1,a2), m3(a3,a4,p[15])));

    if (__all(mloc - mrow <= 8.f)){
        #pragma unroll
        for(int r=0;r<16;r++) p[r] = fexp2(p[r] - mrow);
    } else {
        float mn = fmaxf(mrow, mloc);
        float alpha = fexp2(mrow - mn);
        #pragma unroll
        for(int r=0;r<16;r++) p[r] = fexp2(p[r] - mn);
        #pragma unroll
        for(int r=0;r<16;r++){ Of0[r]*=alpha; Of1[r]*=alpha; }
        lrow *= alpha;
        mrow = mn;
    }
    float s0=(p[0]+p[1])+(p[2]+p[3]), s1=(p[4]+p[5])+(p[6]+p[7]),
          s2=(p[8]+p[9])+(p[10]+p[11]), s3=(p[12]+p[13])+(p[14]+p[15]);
    lrow += pairsum((s0+s1)+(s2+s3));

    unsigned w8[8];
    #pragma unroll
    for(int i=0;i<8;i++) w8[i] = pk2(p[2*i], p[2*i+1]);

    __builtin_amdgcn_s_setprio(1);
    #pragma unroll
    for(int kss=0; kss<2; kss++){
        unsigned W0,W1,W2,W3;
        lswap(w8[4*kss+0], w8[4*kss+2], W0, W2);
        lswap(w8[4*kss+1], w8[4*kss+3], W1, W3);
        union { unsigned u[4]; s16x8 v; } Bf;
        Bf.u[0]=W0; Bf.u[1]=W1; Bf.u[2]=W2; Bf.u[3]=W3;
        Of0 = __builtin_amdgcn_mfma_f32_32x32x16_bf16(vf[0*2+kss], Bf.v, Of0, 0, 0, 0);
        Of1 = __builtin_amdgcn_mfma_f32_32x32x16_bf16(vf[1*2+kss], Bf.v, Of1, 0, 0, 0);
    }
    __builtin_amdgcn_s_setprio(0);
}

__device__ __attribute__((always_inline)) inline
void seg_run(const unsigned short* __restrict__ Qp,
             const char* __restrict__ Kp,
             const char* __restrict__ Vp,
             int j, int ks, int ke, int lane,
             f32x16& Of0, f32x16& Of1, float& mrow, float& lrow){
    int l31 = lane & 31, hi = lane >> 5;
    int q = j*32 + l31;
    int laneoff = lane*16;

    s16x8 Qf[4];
    #pragma unroll
    for(int s=0;s<4;s++)
        Qf[s] = *(const s16x8*)(Qp + (size_t)q*HD + s*16 + hi*8);

    #pragma unroll
    for(int r=0;r<16;r++){ Of0[r]=0.f; Of1[r]=0.f; }
    mrow = -1e30f; lrow = 0.f;

    s16x8 kA[4], kB[4], vv[4];
    int kt = ks;
    loadK(Kp, ks, laneoff, kA);

    // K double-buffered one tile ahead; V single-buffered at tile top
    while (kt + 2 < ke){
        loadV(Vp, kt,   laneoff, vv);
        loadK(Kp, kt+1, laneoff, kB);
        tile_compute(kA, vv, kt,   j, hi, q, Qf, Of0, Of1, mrow, lrow);
        loadV(Vp, kt+1, laneoff, vv);
        loadK(Kp, kt+2, laneoff, kA);
        tile_compute(kB, vv, kt+1, j, hi, q, Qf, Of0, Of1, mrow, lrow);
        kt += 2;
    }
    if (ke - kt == 2){
        loadV(Vp, kt,   laneoff, vv);
        loadK(Kp, kt+1, laneoff, kB);
        tile_compute(kA, vv, kt,   j, hi, q, Qf, Of0, Of1, mrow, lrow);
        loadV(Vp, kt+1, laneoff, vv);
        tile_compute(kB, vv, kt+1, j, hi, q, Qf, Of0, Of1, mrow, lrow);
    } else {
        loadV(Vp, kt, laneoff, vv);
        tile_compute(kA, vv, kt,   j, hi, q, Qf, Of0, Of1, mrow, lrow);
    }
}

__global__ __launch_bounds__(256, 3) void attn_mfma11(const unsigned short* __restrict__ Qh,
                                                      const unsigned short* __restrict__ Kfr,
                                                      const unsigned short* __restrict__ Vfr,
                                                      float* __restrict__ ao){
    __shared__ float Osh[4*2048];     // 32768 B, stride-32 (2 lanes/bank = free)
    __shared__ float Msh[4*32], Lsh[4*32];
    __shared__ int   qid[4];

    int blk = blockIdx.x;
    int bh = blk & 31;               // bh%8 == blk%8 -> K/V stay on one XCD's L2
    int p  = blk >> 5;               // pair index 0..31: qtiles {p, 63-p}
    int b  = bh >> 4;
    int tid = threadIdx.x;
    int wv = tid >> 6;
    int lane = tid & 63;
    int l31 = lane & 31, hi = lane >> 5;

    if (tid < 4) qid[tid] = -1;
    __syncthreads();

    const unsigned short* Qp = Qh + (size_t)bh*TT*HD;
    const char* Kp = (const char*)Kfr + (size_t)bh*262144;
    const char* Vp = (const char*)Vfr + (size_t)bh*262144;

    int jB = 63 - p, jA = p;
    int nB = 64 - p;                 // tiles for qtile B (first in flat list)
    int s = (65*wv) >> 2;            // 0,16,32,48
    int e = (wv==3) ? 65 : ((65*(wv+1)) >> 2);

    int bs = s,               be = (e < nB) ? e : nB;       // B-segment
    int as_ = ((s > nB) ? s : nB) - nB, ae = e - nB;        // A-segment
    bool hasB = bs < be;
    bool hasA = as_ < ae;

    f32x16 Of0, Of1;
    float mr = -1e30f, lr = 0.f;

    if (hasB){
        seg_run(Qp, Kp, Vp, jB, bs, be, lane, Of0, Of1, mr, lr);
        // dump B partial to own slot
        float* Ob = Osh + wv*2048;
        #pragma unroll
        for(int r=0;r<16;r++){
            int d0 = (r&3) + 8*(r>>2) + 4*hi;
            Ob[d0*32 + l31]      = Of0[r];
            Ob[(d0+32)*32 + l31] = Of1[r];
        }
        if (lane < 32){ Msh[wv*32 + l31] = mr; Lsh[wv*32 + l31] = lr; }
        if (lane == 0) qid[wv] = 0;
    }
    if (hasA){
        seg_run(Qp, Kp, Vp, jA, as_, ae, lane, Of0, Of1, mr, lr);
        if (!hasB){
            float* Ob = Osh + wv*2048;
            #pragma unroll
            for(int r=0;r<16;r++){
                int d0 = (r&3) + 8*(r>>2) + 4*hi;
                Ob[d0*32 + l31]      = Of0[r];
                Ob[(d0+32)*32 + l31] = Of1[r];
            }
            if (lane < 32){ Msh[wv*32 + l31] = mr; Lsh[wv*32 + l31] = lr; }
            if (lane == 0) qid[wv] = 1;
        }
    }
    __syncthreads();

    if (hasA && hasB){
        if (wv == 3){
            // sole owner of complete qtile A: store directly from regs
            float invl = 1.0f / lr;
            int q = jA*32 + l31;
            size_t obase = (size_t)(b*TT + q)*DIM + (bh & 15)*HD + 4*hi;
            #pragma unroll
            for(int u=0;u<4;u++){
                float4 o0, o1;
                o0.x=Of0[4*u+0]*invl; o0.y=Of0[4*u+1]*invl; o0.z=Of0[4*u+2]*invl; o0.w=Of0[4*u+3]*invl;
                o1.x=Of1[4*u+0]*invl; o1.y=Of1[4*u+1]*invl; o1.z=Of1[4*u+2]*invl; o1.w=Of1[4*u+3]*invl;
                *(float4*)(ao + obase + 8*u)      = o0;
                *(float4*)(ao + obase + 32 + 8*u) = o1;
            }
        } else {
            // fold reg A-partial into wave (wv+1)'s slot (pure-A, already dumped)
            int t = wv + 1;
            float mt = Msh[t*32 + l31];
            float ms = fmaxf(mt, mr);
            float ct = fexp2(mt - ms), cr = fexp2(mr - ms);
            float* Ob = Osh + t*2048;
            #pragma unroll
            for(int r=0;r<16;r++){
                int d0 = (r&3) + 8*(r>>2) + 4*hi;
                Ob[d0*32 + l31]      = ct*Ob[d0*32 + l31]      + cr*Of0[r];
                Ob[(d0+32)*32 + l31] = ct*Ob[(d0+32)*32 + l31] + cr*Of1[r];
            }
            if (lane < 32){
                Lsh[t*32 + l31] = ct*Lsh[t*32 + l31] + cr*lr;
                Msh[t*32 + l31] = ms;
            }
        }
    }
    __syncthreads();

    // ---- final merges: wave0 -> qtile B, wave1 -> qtile A (if slots exist) ----
    if (wv < 2){
        bool any = false;
        #pragma unroll
        for(int sl=0; sl<4; sl++) any |= (qid[sl] == wv);
        if (any){
            float Om0[16], Om1[16];
            #pragma unroll
            for(int r=0;r<16;r++){ Om0[r]=0.f; Om1[r]=0.f; }
            float mst = -1e30f;
            #pragma unroll
            for(int sl=0; sl<4; sl++)
                if (qid[sl] == wv) mst = fmaxf(mst, Msh[sl*32 + l31]);
            float lst = 0.f;
            #pragma unroll
            for(int sl=0; sl<4; sl++){
                if (qid[sl] == wv){
                    float c = fexp2(Msh[sl*32 + l31] - mst);
                    lst += c * Lsh[sl*32 + l31];
                    const float* Ob = Osh + sl*2048;
                    #pragma unroll
                    for(int r=0;r<16;r++){
                        int d0 = (r&3) + 8*(r>>2) + 4*hi;
                        Om0[r] += c * Ob[d0*32 + l31];
                        Om1[r] += c * Ob[(d0+32)*32 + l31];
                    }
                }
            }
            float invl = 1.0f / lst;
            int j = (wv == 0) ? jB : jA;
            int q = j*32 + l31;
            size_t obase = (size_t)(b*TT + q)*DIM + (bh & 15)*HD + 4*hi;
            #pragma unroll
            for(int u=0;u<4;u++){
                float4 o0, o1;
                o0.x=Om0[4*u+0]*invl; o0.y=Om0[4*u+1]*invl; o0.z=Om0[4*u+2]*invl; o0.w=Om0[4*u+3]*invl;
                o1.x=Om1[4*u+0]*invl; o1.y=Om1[4*u+1]*invl; o1.z=Om1[4*u+2]*invl; o1.w=Om1[4*u+3]*invl;
                *(float4*)(ao + obase + 8*u)      = o0;
                *(float4*)(ao + obase + 32 + 8*u) = o1;
            }
        }
    }
}

// ---------------- launch ----------------
extern "C" void kernel_launch(void* const* d_in, const int* in_sizes, int n_in,
                              void* d_out, int out_size, void* d_ws, size_t ws_size,
                              hipStream_t stream){
    const float* x    = (const float*)d_in[0];
    const float* cosb = (const float*)d_in[1];
    const float* sinb = (const float*)d_in[2];
    const float* wq_w = (const float*)d_in[3];
    const float* wk_w = (const float*)d_in[4];
    const float* wv_w = (const float*)d_in[5];
    const float* wo_w = (const float*)d_in[6];
    float* out = (float*)d_out;

    char* cw = (char*)d_ws;
    const size_t MB = 1048576;
    char*  wpk   = cw;                             // [0,4MB) fragment-order weights
    float* wsall = (float*)(cw + 4*MB);            // 128 KB
    float* srow1 = (float*)(cw + 4*MB + 131072);   // 16 KB
    float* srow2 = (float*)(cw + 4*MB + 147456);   // 16 KB
    char*  xpk   = cw + 5*MB;                      // [5,9MB)  fragment-order activations
    char*  xpk2  = cw + 9*MB;                      // [9,13MB)
    unsigned short* Qh = (unsigned short*)(cw + 13*MB);  // [13,21MB) Q row-major
    unsigned short* Kf = (unsigned short*)(cw + 21*MB);  // [21,29MB) K frag-order
    unsigned short* Vf = (unsigned short*)(cw + 29*MB);  // [29,37MB) V^T frag-order
    float* ao    = (float*)(cw + 37*MB);           // [37,53MB)

    quant_all<<<1024 + MROWS, 256, 0, stream>>>(x, wq_w, wk_w, wv_w, wo_w,
                                                wpk, wsall, xpk, srow1);

    gemm_qkv<<<dim3(24, MROWS/64), 128, 0, stream>>>(xpk, wpk, wsall, srow1,
                                                     cosb, sinb, Qh, Kf, Vf);

    attn_mfma11<<<1024, 256, 0, stream>>>(Qh, Kf, Vf, ao);

    quant_x_i8<<<MROWS, 256, 0, stream>>>(ao, xpk2, srow2);
    gemm_i8<<<dim3(DIM/128, MROWS/64), 256, 0, stream>>>(xpk2, wpk + 3*MB,
                                                         wsall + 3*8192, srow2, out);
}

// Round 11
// 182.272 us; speedup vs baseline: 1.1612x; 1.1612x over previous
//
#include <hip/hip_runtime.h>
#include <math.h>

#define DIM   1024
#define NH    16
#define HD    64
#define GRP   128
#define BB    2
#define TT    2048
#define MROWS (BB*TT)   // 4096

typedef __attribute__((ext_vector_type(8))) short s16x8;
typedef __attribute__((ext_vector_type(4))) float f32x4;
typedef __attribute__((ext_vector_type(16))) float f32x16;
typedef __attribute__((ext_vector_type(4))) int   i32x4;
typedef __attribute__((ext_vector_type(16))) int  i32x16;
typedef __attribute__((ext_vector_type(2))) unsigned u32x2;

__device__ inline float wave_max(float v){
    for(int off=32; off; off>>=1) v = fmaxf(v, __shfl_xor(v, off));
    return v;
}

__device__ inline unsigned short f2bf(float x){
    union { float f; unsigned u; } v; v.f = x;
    unsigned r = v.u + 0x7fffu + ((v.u >> 16) & 1u);
    return (unsigned short)(r >> 16);
}

#if __has_builtin(__builtin_amdgcn_cvt_pk_bf16_f32)
typedef __bf16 bf16x2 __attribute__((ext_vector_type(2)));
__device__ inline unsigned pk2(float a, float b){
    union { bf16x2 v; unsigned u; } c;
    c.v = __builtin_amdgcn_cvt_pk_bf16_f32(a, b);
    return c.u;
}
#else
__device__ inline unsigned pk2(float a, float b){
    return (unsigned)f2bf(a) | ((unsigned)f2bf(b) << 16);
}
#endif

#if __has_builtin(__builtin_amdgcn_exp2f)
__device__ inline float fexp2(float x){ return __builtin_amdgcn_exp2f(x); }
#else
__device__ inline float fexp2(float x){ return exp2f(x); }
#endif

__device__ inline float m3(float a, float b, float c){ return fmaxf(fmaxf(a,b), c); }

// lswap(a,b) -> lo, hi via one v_permlane32_swap_b32 (VALU, no DS).
__device__ inline void lswap(unsigned a, unsigned b, unsigned &lo, unsigned &hi){
#if __has_builtin(__builtin_amdgcn_permlane32_swap)
    u32x2 r = __builtin_amdgcn_permlane32_swap(a, b, false, false);
    lo = r[0]; hi = r[1];
#else
    bool h = (threadIdx.x & 32) != 0;
    unsigned sa = (unsigned)__shfl_xor((int)a, 32);
    unsigned sb = (unsigned)__shfl_xor((int)b, 32);
    lo = h ? sb : a;
    hi = h ? b : sa;
#endif
}

__device__ inline float pairmax(float x){
    union { float f; unsigned u; } a, lo, hi;
    a.f = x;
    lswap(a.u, a.u, lo.u, hi.u);
    return fmaxf(lo.f, hi.f);
}
__device__ inline float pairsum(float x){
    union { float f; unsigned u; } a, lo, hi;
    a.f = x;
    lswap(a.u, a.u, lo.u, hi.u);
    return lo.f + hi.f;
}

__device__ inline i32x16 zero16(){
    i32x16 z;
    #pragma unroll
    for(int i=0;i<16;i++) z[i]=0;
    return z;
}

#define QSC 0.18033688011112042f   // 0.125 * log2(e)

// int8 fragment order (GEMMs): for 32-row block rb, entry ((g*4+s)*64+lane)*16
// holds rows[lane&31], k = g*128 + (s*2 + (lane>>5))*16 .. +15.
//
// bf16 32x32 A-fragment order (attn K): per bh, 32-key tile kt, s in [0,4):
//   byte addr = bh*262144 + kt*4096 + s*1024 + lane*16
//   contents  = K[t = kt*32 + (lane&31)][d = s*16 + (lane>>5)*8 + 0..7]
// bf16 V^T A-fragment order (attn V): per bh, tile kt, hv,ks in {0,1}:
//   byte addr = bh*262144 + kt*4096 + (hv*2+ks)*1024 + lane*16
//   contents  = V[t = kt*32 + ks*16 + (lane>>5)*8 + 0..7][d = 32*hv + (lane&31)]

// ---------------- fused quantization -> fragment-order int8 ----------------
__global__ __launch_bounds__(256) void quant_all(const float* __restrict__ x,
                                                 const float* __restrict__ w0,
                                                 const float* __restrict__ w1,
                                                 const float* __restrict__ w2,
                                                 const float* __restrict__ w3,
                                                 char* __restrict__ wpk,
                                                 float* __restrict__ wsall,
                                                 char* __restrict__ xpk,
                                                 float* __restrict__ srow){
    int blk = blockIdx.x;
    int tid = threadIdx.x;
    if (blk < 1024){
        int widx = blk >> 8;
        const float* w = (widx==0)?w0 : (widx==1)?w1 : (widx==2)?w2 : w3;
        int gloc = (blk & 255)*32 + (tid >> 3);   // group index = n*8 + g
        int j = tid & 7;
        const float* p = w + (size_t)gloc*GRP;
        // contiguous 64B chunk per thread, values kept in regs for the quant pass
        float4 vv[4];
        float r = 0.f;
        #pragma unroll
        for(int c4=0;c4<4;c4++){
            vv[c4] = *(const float4*)(p + j*16 + c4*4);
            r += (fabsf(vv[c4].x)+fabsf(vv[c4].y)) + (fabsf(vv[c4].z)+fabsf(vv[c4].w));
        }
        r += __shfl_xor(r, 1);
        r += __shfl_xor(r, 2);
        r += __shfl_xor(r, 4);
        float ws = r/(float)GRP + 1e-5f;
        if (j == 0) wsall[widx*8192 + gloc] = ws;
        float rws = 1.f/ws;       // one divide instead of 64
        int n = gloc >> 3, g = gloc & 7;
        char* base = wpk + (size_t)widx*1048576 + (size_t)(n>>5)*32768
                   + (size_t)(((g*4 + (j>>1))*64 + ((j&1)*32 + (n&31)))*16);
        #pragma unroll
        for(int c4=0;c4<4;c4++){
            float4 v = vv[c4];
            int b0 = (int)fminf(fmaxf(rintf(v.x*rws),-1.f),1.f);
            int b1 = (int)fminf(fmaxf(rintf(v.y*rws),-1.f),1.f);
            int b2 = (int)fminf(fmaxf(rintf(v.z*rws),-1.f),1.f);
            int b3 = (int)fminf(fmaxf(rintf(v.w*rws),-1.f),1.f);
            *(int*)(base + c4*4) = (b0&0xff) | ((b1&0xff)<<8) | ((b2&0xff)<<16) | ((b3&0xff)<<24);
        }
    } else {
        int row = blk - 1024;
        const float* p = x + (size_t)row*DIM;
        float4 v = *(const float4*)(p + tid*4);
        float m = fmaxf(fmaxf(fabsf(v.x),fabsf(v.y)), fmaxf(fabsf(v.z),fabsf(v.w)));
        m = wave_max(m);
        __shared__ float red[4];
        if ((tid&63)==0) red[tid>>6] = m;
        __syncthreads();
        m = fmaxf(fmaxf(red[0],red[1]), fmaxf(red[2],red[3]));
        float s = 127.f/(m+1e-5f);
        int a0 = (int)fminf(fmaxf(rintf(v.x*s),-128.f),127.f);
        int a1 = (int)fminf(fmaxf(rintf(v.y*s),-128.f),127.f);
        int a2 = (int)fminf(fmaxf(rintf(v.z*s),-128.f),127.f);
        int a3 = (int)fminf(fmaxf(rintf(v.w*s),-128.f),127.f);
        int pk = (a0&0xff) | ((a1&0xff)<<8) | ((a2&0xff)<<16) | ((a3&0xff)<<24);
        int g = tid >> 5, chunk = (tid&31) >> 2;
        *(int*)(xpk + (size_t)(row>>5)*32768
               + (size_t)(((g*4 + (chunk>>1))*64 + ((chunk&1)*32 + (row&31)))*16)
               + (tid&3)*4) = pk;
        if (tid==0) srow[row] = s;
    }
}

// ---------------- activation quantization -> fragment-order (attn output) ----------------
__global__ __launch_bounds__(256) void quant_x_i8(const float* __restrict__ x,
                                                  char* __restrict__ xpk,
                                                  float* __restrict__ srow){
    int row = blockIdx.x;
    int tid = threadIdx.x;
    const float* p = x + (size_t)row*DIM;
    float4 v = *(const float4*)(p + tid*4);
    float m = fmaxf(fmaxf(fabsf(v.x),fabsf(v.y)), fmaxf(fabsf(v.z),fabsf(v.w)));
    m = wave_max(m);
    __shared__ float red[4];
    if ((tid&63)==0) red[tid>>6] = m;
    __syncthreads();
    m = fmaxf(fmaxf(red[0],red[1]), fmaxf(red[2],red[3]));
    float s = 127.f/(m+1e-5f);
    int a0 = (int)fminf(fmaxf(rintf(v.x*s),-128.f),127.f);
    int a1 = (int)fminf(fmaxf(rintf(v.y*s),-128.f),127.f);
    int a2 = (int)fminf(fmaxf(rintf(v.z*s),-128.f),127.f);
    int a3 = (int)fminf(fmaxf(rintf(v.w*s),-128.f),127.f);
    int pk = (a0&0xff) | ((a1&0xff)<<8) | ((a2&0xff)<<16) | ((a3&0xff)<<24);
    int g = tid >> 5, chunk = (tid&31) >> 2;
    *(int*)(xpk + (size_t)(row>>5)*32768
           + (size_t)(((g*4 + (chunk>>1))*64 + ((chunk&1)*32 + (row&31)))*16)
           + (tid&3)*4) = pk;
    if (tid==0) srow[row] = s;
}

// ---------------- barrier-free int8 MFMA K-loops on fragment-order operands ----------------
// 32x128-per-wave variant (gemm_i8; keeps 2 waves/SIMD TLP for the small GEMM)
__device__ inline void kloop_pk(const char* __restrict__ A,
                                const char* __restrict__ B0,
                                const char* __restrict__ B1,
                                const float wsr[2][8],
                                float facc[2][16]){
    int lane = threadIdx.x & 63;
    #pragma unroll
    for(int g=0; g<8; g++){
        i32x16 iacc[2];
        iacc[0]=zero16(); iacc[1]=zero16();
        #pragma unroll
        for(int s=0; s<4; s++){
            size_t off = (size_t)(((g*4+s)*64 + lane)*16);
            i32x4 afr = *(const i32x4*)(A  + off);
            i32x4 b0  = *(const i32x4*)(B0 + off);
            i32x4 b1  = *(const i32x4*)(B1 + off);
            iacc[0] = __builtin_amdgcn_mfma_i32_32x32x32_i8(afr, b0, iacc[0], 0, 0, 0);
            iacc[1] = __builtin_amdgcn_mfma_i32_32x32x32_i8(afr, b1, iacc[1], 0, 0, 0);
        }
        #pragma unroll
        for(int jt=0; jt<2; jt++)
            #pragma unroll
            for(int r=0;r<16;r++)
                facc[jt][r] += (float)iacc[jt][r] * wsr[jt][g];
    }
}

// 64x64-per-wave variant (gemm_qkv): square wave tile -> 1.0 KB loaded per
// MFMA vs 1.5 for 32x128. Kernel-wide load traffic -33%.
__device__ inline void kloop64(const char* __restrict__ A0,
                               const char* __restrict__ B0,
                               const float wsr[2][8],
                               float facc[2][2][16]){
    int lane = threadIdx.x & 63;
    const char* A1 = A0 + 32768;
    const char* B1 = B0 + 32768;
    #pragma unroll
    for(int g=0; g<8; g++){
        i32x16 i00=zero16(), i01=zero16(), i10=zero16(), i11=zero16();
        #pragma unroll
        for(int s=0; s<4; s++){
            size_t off = (size_t)(((g*4+s)*64 + lane)*16);
            i32x4 a0 = *(const i32x4*)(A0 + off);
            i32x4 a1 = *(const i32x4*)(A1 + off);
            i32x4 b0 = *(const i32x4*)(B0 + off);
            i32x4 b1 = *(const i32x4*)(B1 + off);
            i00 = __builtin_amdgcn_mfma_i32_32x32x32_i8(a0, b0, i00, 0, 0, 0);
            i01 = __builtin_amdgcn_mfma_i32_32x32x32_i8(a0, b1, i01, 0, 0, 0);
            i10 = __builtin_amdgcn_mfma_i32_32x32x32_i8(a1, b0, i10, 0, 0, 0);
            i11 = __builtin_amdgcn_mfma_i32_32x32x32_i8(a1, b1, i11, 0, 0, 0);
        }
        #pragma unroll
        for(int r=0;r<16;r++){
            facc[0][0][r] += (float)i00[r] * wsr[0][g];
            facc[0][1][r] += (float)i01[r] * wsr[1][g];
            facc[1][0][r] += (float)i10[r] * wsr[0][g];
            facc[1][1][r] += (float)i11[r] * wsr[1][g];
        }
    }
}

// ---------------- fused QKV int8 GEMM + RoPE/bf16 pack epilogue ----------------
// grid (24, 64), 128 threads: 2 waves, each computing 64x64 (kloop64).
__global__ __launch_bounds__(128, 2) void gemm_qkv(const char* __restrict__ Apk,
                                                   const char* __restrict__ wpk,
                                                   const float* __restrict__ wsall,
                                                   const float* __restrict__ srow,
                                                   const float* __restrict__ cosb,
                                                   const float* __restrict__ sinb,
                                                   unsigned short* __restrict__ Qh,
                                                   unsigned short* __restrict__ Kf,
                                                   unsigned short* __restrict__ Vf){
    __shared__ float T[64*132];   // 33792 B, epilogue only

    int nt = blockIdx.x;
    int widx = nt >> 3;
    int n0 = (nt & 7)*128;
    int m0 = blockIdx.y*64;
    const char* W = wpk + (size_t)widx*1048576;
    const float* wsb = wsall + widx*8192;

    int tid = threadIdx.x;
    int w = tid >> 6, lane = tid & 63;   // w: column half (64 cols per wave)
    int l31 = lane & 31, lh = lane >> 5;

    float wsr[2][8];
    #pragma unroll
    for(int ci=0; ci<2; ci++){
        int col = n0 + w*64 + ci*32 + l31;
        float4 q0 = *(const float4*)(wsb + (size_t)col*8);
        float4 q1 = *(const float4*)(wsb + (size_t)col*8 + 4);
        wsr[ci][0]=q0.x; wsr[ci][1]=q0.y; wsr[ci][2]=q0.z; wsr[ci][3]=q0.w;
        wsr[ci][4]=q1.x; wsr[ci][5]=q1.y; wsr[ci][6]=q1.z; wsr[ci][7]=q1.w;
    }

    float facc[2][2][16];
    #pragma unroll
    for(int ri=0;ri<2;ri++)
        #pragma unroll
        for(int ci=0;ci<2;ci++)
            #pragma unroll
            for(int r=0;r<16;r++) facc[ri][ci][r]=0.f;

    const char* A0 = Apk + (size_t)(m0>>5)*32768;
    const char* B0 = W   + (size_t)((n0>>5) + w*2)*32768;
    kloop64(A0, B0, wsr, facc);

    // ---- dequant into LDS fp32 tile ----
    #pragma unroll
    for(int ri=0; ri<2; ri++)
        #pragma unroll
        for(int r=0; r<16; r++){
            int rowl = ri*32 + (r&3) + 8*(r>>2) + 4*lh;
            float rsv = 1.f / srow[m0 + rowl];
            #pragma unroll
            for(int ci=0; ci<2; ci++)
                T[rowl*132 + w*64 + ci*32 + l31] = facc[ri][ci][r] * rsv;
        }
    __syncthreads();

    int bglob = m0 >> 11;            // batch, block-uniform
    int h0 = n0 >> 6;                // first of the 2 heads this block covers
    int kt0 = (m0 & (TT-1)) >> 5;    // first 32-key tile this block covers

    if (widx == 0){
        // ---- Q: row-order bf16, RoPE + QSC ----
        #pragma unroll
        for(int i=0;i<2;i++){
            int e = tid + 128*i;
            int row = e & 63, chunk = e >> 6;
            int t = (m0 + row) & (TT-1);
            const float* Tr = T + row*132 + chunk*32;
            int colbase = n0 + chunk*32;
            int h = colbase >> 6;
            int d0 = colbase & 63;
            int bh = bglob*NH + h;
            unsigned short* dst = Qh + ((size_t)bh*TT + t)*HD + d0;
            int p0 = d0 >> 1;
            __align__(16) unsigned short ob[32];
            #pragma unroll
            for(int pp=0; pp<16; pp++){
                float c = cosb[t*32 + p0 + pp], s = sinb[t*32 + p0 + pp];
                float ev = Tr[2*pp], ov = Tr[2*pp+1];
                ob[2*pp]   = f2bf((ev*c - ov*s)*QSC);
                ob[2*pp+1] = f2bf((ev*s + ov*c)*QSC);
            }
            #pragma unroll
            for(int c4=0;c4<4;c4++)
                *(s16x8*)(dst + c4*8) = *(s16x8*)(ob + c4*8);
        }
    } else if (widx == 1){
        // ---- K: 32x32 A-fragment order bf16, RoPE ----
        #pragma unroll
        for(int i=0;i<8;i++){
            int e = tid + 128*i;
            int hh = e >> 9, ktl = (e >> 8)&1, s = (e >> 6)&3;
            int ln = e & 63, li = ln & 31, hi2 = ln >> 5;
            int row = ktl*32 + li;
            int t = (m0 + row) & (TT-1);
            int d0 = s*16 + hi2*8;
            const float* Tr = T + row*132 + hh*64 + d0;
            int p0 = d0 >> 1;
            __align__(16) unsigned short ob[8];
            #pragma unroll
            for(int pp=0;pp<4;pp++){
                float c = cosb[t*32 + p0 + pp], sn = sinb[t*32 + p0 + pp];
                float ev = Tr[2*pp], ov = Tr[2*pp+1];
                ob[2*pp]   = f2bf(ev*c - ov*sn);
                ob[2*pp+1] = f2bf(ev*sn + ov*c);
            }
            int bh = bglob*NH + h0 + hh;
            size_t dst = (size_t)bh*262144 + (size_t)(((kt0 + ktl)*4 + s)*64 + ln)*16;
            *(s16x8*)((char*)Kf + dst) = *(s16x8*)ob;
        }
    } else {
        // ---- V: V^T A-fragment order bf16 ----
        #pragma unroll
        for(int i=0;i<8;i++){
            int e = tid + 128*i;
            int hh = e >> 9, ktl = (e >> 8)&1, hv = (e >> 7)&1, ks = (e >> 6)&1;
            int ln = e & 63, li = ln & 31, hi2 = ln >> 5;
            int tl0 = ktl*32 + ks*16 + hi2*8;
            int col = hh*64 + 32*hv + li;
            __align__(16) unsigned short ob[8];
            #pragma unroll
            for(int jj=0;jj<8;jj++)
                ob[jj] = f2bf(T[(tl0+jj)*132 + col]);
            int bh = bglob*NH + h0 + hh;
            size_t dst = (size_t)bh*262144 + (size_t)((((kt0 + ktl)*2 + hv)*2 + ks)*64 + ln)*16;
            *(s16x8*)((char*)Vf + dst) = *(s16x8*)ob;
        }
    }
}

// ---------------- barrier-free int8 MFMA GEMM (output projection) ----------------
__global__ __launch_bounds__(256) void gemm_i8(const char* __restrict__ Apk,
                                               const char* __restrict__ Wp,
                                               const float* __restrict__ wsb,
                                               const float* __restrict__ srow,
                                               float* __restrict__ C){
    int tid = threadIdx.x;
    int w = tid >> 6, lane = tid & 63;
    int wm = w & 1, wn = w >> 1;
    int m0 = blockIdx.y*64, n0 = blockIdx.x*128;
    int l31 = lane & 31, lh = lane >> 5;

    float wsr[2][8];
    #pragma unroll
    for(int jt=0; jt<2; jt++){
        int col = n0 + (wn*2+jt)*32 + l31;
        float4 q0 = *(const float4*)(wsb + (size_t)col*8);
        float4 q1 = *(const float4*)(wsb + (size_t)col*8 + 4);
        wsr[jt][0]=q0.x; wsr[jt][1]=q0.y; wsr[jt][2]=q0.z; wsr[jt][3]=q0.w;
        wsr[jt][4]=q1.x; wsr[jt][5]=q1.y; wsr[jt][6]=q1.z; wsr[jt][7]=q1.w;
    }

    float facc[2][16];
    #pragma unroll
    for(int b=0;b<2;b++)
        #pragma unroll
        for(int r=0;r<16;r++) facc[b][r]=0.f;

    const char* A  = Apk + (size_t)((m0>>5) + wm)*32768;
    const char* B0 = Wp  + (size_t)((n0>>5) + wn*2)*32768;
    const char* B1 = B0 + 32768;
    kloop_pk(A, B0, B1, wsr, facc);

    #pragma unroll
    for(int r=0; r<16; r++){
        int rowl = wm*32 + (r&3) + 8*(r>>2) + 4*lh;
        float rsv = 1.f / srow[m0 + rowl];
        #pragma unroll
        for(int jt=0; jt<2; jt++){
            int col = n0 + (wn*2+jt)*32 + l31;
            C[(size_t)(m0+rowl)*DIM + col] = facc[jt][r] * rsv;
        }
    }
}

// ---------------- MFMA flash attention v9: spill-free, reg-double-buffered ----------------
// Best verified attn config (round 9, total 183.2us). v10 cross-tile ILP was
// neutral-negative; v11's (256,3) occupancy push caused catastrophic scratch
// spill (VGPR 84, +37MB scratch traffic). (256,2) + ~200 VGPR is the optimum.
__device__ __attribute__((always_inline)) inline
void tile_load(const char* __restrict__ Kp, const char* __restrict__ Vp,
               int kt, int laneoff, s16x8 kc[4], s16x8 vf[4]){
    const char* kb = Kp + (size_t)kt*4096 + laneoff;
    const char* vb = Vp + (size_t)kt*4096 + laneoff;
    #pragma unroll
    for(int s=0;s<4;s++) kc[s] = *(const s16x8*)(kb + s*1024);
    #pragma unroll
    for(int i=0;i<4;i++) vf[i] = *(const s16x8*)(vb + i*1024);
}

__device__ __attribute__((always_inline)) inline
void tile_compute(const s16x8 kc[4], const s16x8 vf[4], int kt, int j,
                  int hi, int q, const s16x8 Qf[4],
                  f32x16& Of0, f32x16& Of1, float& mrow, float& lrow){
    f32x16 S;
    #pragma unroll
    for(int r=0;r<16;r++) S[r]=0.f;
    __builtin_amdgcn_s_setprio(1);
    #pragma unroll
    for(int s=0;s<4;s++)
        S = __builtin_amdgcn_mfma_f32_32x32x16_bf16(kc[s], Qf[s], S, 0, 0, 0);
    __builtin_amdgcn_s_setprio(0);

    float p[16];
    if (kt == j){
        #pragma unroll
        for(int r=0;r<16;r++){
            int key = kt*32 + (r&3) + 8*(r>>2) + 4*hi;
            p[r] = (key > q) ? -1e30f : S[r];
        }
    } else {
        #pragma unroll
        for(int r=0;r<16;r++) p[r] = S[r];
    }

    float a0=m3(p[0],p[1],p[2]), a1=m3(p[3],p[4],p[5]), a2=m3(p[6],p[7],p[8]),
          a3=m3(p[9],p[10],p[11]), a4=m3(p[12],p[13],p[14]);
    float mloc = pairmax(fmaxf(m3(a0,a1,a2), m3(a3,a4,p[15])));

    if (__all(mloc - mrow <= 8.f)){
        #pragma unroll
        for(int r=0;r<16;r++) p[r] = fexp2(p[r] - mrow);
    } else {
        float mn = fmaxf(mrow, mloc);
        float alpha = fexp2(mrow - mn);
        #pragma unroll
        for(int r=0;r<16;r++) p[r] = fexp2(p[r] - mn);
        #pragma unroll
        for(int r=0;r<16;r++){ Of0[r]*=alpha; Of1[r]*=alpha; }
        lrow *= alpha;
        mrow = mn;
    }
    float s0=(p[0]+p[1])+(p[2]+p[3]), s1=(p[4]+p[5])+(p[6]+p[7]),
          s2=(p[8]+p[9])+(p[10]+p[11]), s3=(p[12]+p[13])+(p[14]+p[15]);
    lrow += pairsum((s0+s1)+(s2+s3));

    unsigned w8[8];
    #pragma unroll
    for(int i=0;i<8;i++) w8[i] = pk2(p[2*i], p[2*i+1]);

    __builtin_amdgcn_s_setprio(1);
    #pragma unroll
    for(int kss=0; kss<2; kss++){
        unsigned W0,W1,W2,W3;
        lswap(w8[4*kss+0], w8[4*kss+2], W0, W2);
        lswap(w8[4*kss+1], w8[4*kss+3], W1, W3);
        union { unsigned u[4]; s16x8 v; } Bf;
        Bf.u[0]=W0; Bf.u[1]=W1; Bf.u[2]=W2; Bf.u[3]=W3;
        Of0 = __builtin_amdgcn_mfma_f32_32x32x16_bf16(vf[0*2+kss], Bf.v, Of0, 0, 0, 0);
        Of1 = __builtin_amdgcn_mfma_f32_32x32x16_bf16(vf[1*2+kss], Bf.v, Of1, 0, 0, 0);
    }
    __builtin_amdgcn_s_setprio(0);
}

__device__ __attribute__((always_inline)) inline
void seg_run(const unsigned short* __restrict__ Qp,
             const char* __restrict__ Kp,
             const char* __restrict__ Vp,
             int j, int ks, int ke, int lane,
             f32x16& Of0, f32x16& Of1, float& mrow, float& lrow){
    int l31 = lane & 31, hi = lane >> 5;
    int q = j*32 + l31;
    int laneoff = lane*16;

    s16x8 Qf[4];
    #pragma unroll
    for(int s=0;s<4;s++)
        Qf[s] = *(const s16x8*)(Qp + (size_t)q*HD + s*16 + hi*8);

    #pragma unroll
    for(int r=0;r<16;r++){ Of0[r]=0.f; Of1[r]=0.f; }
    mrow = -1e30f; lrow = 0.f;

    s16x8 kA[4], vA[4], kB[4], vB[4];
    int kt = ks;
    tile_load(Kp, Vp, kt, laneoff, kA, vA);

    // pair-pipelined main loop: load one tile ahead, alternating buffers
    while (kt + 2 < ke){
        tile_load(Kp, Vp, kt+1, laneoff, kB, vB);
        tile_compute(kA, vA, kt,   j, hi, q, Qf, Of0, Of1, mrow, lrow);
        tile_load(Kp, Vp, kt+2, laneoff, kA, vA);
        tile_compute(kB, vB, kt+1, j, hi, q, Qf, Of0, Of1, mrow, lrow);
        kt += 2;
    }
    if (ke - kt == 2){
        tile_load(Kp, Vp, kt+1, laneoff, kB, vB);
        tile_compute(kA, vA, kt,   j, hi, q, Qf, Of0, Of1, mrow, lrow);
        tile_compute(kB, vB, kt+1, j, hi, q, Qf, Of0, Of1, mrow, lrow);
    } else {
        tile_compute(kA, vA, kt,   j, hi, q, Qf, Of0, Of1, mrow, lrow);
    }
}

__global__ __launch_bounds__(256, 2) void attn_mfma9(const unsigned short* __restrict__ Qh,
                                                     const unsigned short* __restrict__ Kfr,
                                                     const unsigned short* __restrict__ Vfr,
                                                     float* __restrict__ ao){
    __shared__ float Osh[4*2048];     // 32768 B, stride-32 (2 lanes/bank = free)
    __shared__ float Msh[4*32], Lsh[4*32];
    __shared__ int   qid[4];

    int blk = blockIdx.x;
    int bh = blk & 31;               // bh%8 == blk%8 -> K/V stay on one XCD's L2
    int p  = blk >> 5;               // pair index 0..31: qtiles {p, 63-p}
    int b  = bh >> 4;
    int tid = threadIdx.x;
    int wv = tid >> 6;
    int lane = tid & 63;
    int l31 = lane & 31, hi = lane >> 5;

    if (tid < 4) qid[tid] = -1;
    __syncthreads();

    const unsigned short* Qp = Qh + (size_t)bh*TT*HD;
    const char* Kp = (const char*)Kfr + (size_t)bh*262144;
    const char* Vp = (const char*)Vfr + (size_t)bh*262144;

    int jB = 63 - p, jA = p;
    int nB = 64 - p;                 // tiles for qtile B (first in flat list)
    int s = (65*wv) >> 2;            // 0,16,32,48
    int e = (wv==3) ? 65 : ((65*(wv+1)) >> 2);

    int bs = s,               be = (e < nB) ? e : nB;       // B-segment
    int as_ = ((s > nB) ? s : nB) - nB, ae = e - nB;        // A-segment
    bool hasB = bs < be;
    bool hasA = as_ < ae;

    f32x16 Of0, Of1;
    float mr = -1e30f, lr = 0.f;

    if (hasB){
        seg_run(Qp, Kp, Vp, jB, bs, be, lane, Of0, Of1, mr, lr);
        // dump B partial to own slot
        float* Ob = Osh + wv*2048;
        #pragma unroll
        for(int r=0;r<16;r++){
            int d0 = (r&3) + 8*(r>>2) + 4*hi;
            Ob[d0*32 + l31]      = Of0[r];
            Ob[(d0+32)*32 + l31] = Of1[r];
        }
        if (lane < 32){ Msh[wv*32 + l31] = mr; Lsh[wv*32 + l31] = lr; }
        if (lane == 0) qid[wv] = 0;
    }
    if (hasA){
        seg_run(Qp, Kp, Vp, jA, as_, ae, lane, Of0, Of1, mr, lr);
        if (!hasB){
            float* Ob = Osh + wv*2048;
            #pragma unroll
            for(int r=0;r<16;r++){
                int d0 = (r&3) + 8*(r>>2) + 4*hi;
                Ob[d0*32 + l31]      = Of0[r];
                Ob[(d0+32)*32 + l31] = Of1[r];
            }
            if (lane < 32){ Msh[wv*32 + l31] = mr; Lsh[wv*32 + l31] = lr; }
            if (lane == 0) qid[wv] = 1;
        }
    }
    __syncthreads();

    if (hasA && hasB){
        if (wv == 3){
            // sole owner of complete qtile A: store directly from regs
            float invl = 1.0f / lr;
            int q = jA*32 + l31;
            size_t obase = (size_t)(b*TT + q)*DIM + (bh & 15)*HD + 4*hi;
            #pragma unroll
            for(int u=0;u<4;u++){
                float4 o0, o1;
                o0.x=Of0[4*u+0]*invl; o0.y=Of0[4*u+1]*invl; o0.z=Of0[4*u+2]*invl; o0.w=Of0[4*u+3]*invl;
                o1.x=Of1[4*u+0]*invl; o1.y=Of1[4*u+1]*invl; o1.z=Of1[4*u+2]*invl; o1.w=Of1[4*u+3]*invl;
                *(float4*)(ao + obase + 8*u)      = o0;
                *(float4*)(ao + obase + 32 + 8*u) = o1;
            }
        } else {
            // fold reg A-partial into wave (wv+1)'s slot (pure-A, already dumped)
            int t = wv + 1;
            float mt = Msh[t*32 + l31];
            float ms = fmaxf(mt, mr);
            float ct = fexp2(mt - ms), cr = fexp2(mr - ms);
            float* Ob = Osh + t*2048;
            #pragma unroll
            for(int r=0;r<16;r++){
                int d0 = (r&3) + 8*(r>>2) + 4*hi;
                Ob[d0*32 + l31]      = ct*Ob[d0*32 + l31]      + cr*Of0[r];
                Ob[(d0+32)*32 + l31] = ct*Ob[(d0+32)*32 + l31] + cr*Of1[r];
            }
            if (lane < 32){
                Lsh[t*32 + l31] = ct*Lsh[t*32 + l31] + cr*lr;
                Msh[t*32 + l31] = ms;
            }
        }
    }
    __syncthreads();

    // ---- final merges: wave0 -> qtile B, wave1 -> qtile A (if slots exist) ----
    if (wv < 2){
        bool any = false;
        #pragma unroll
        for(int sl=0; sl<4; sl++) any |= (qid[sl] == wv);
        if (any){
            float Om0[16], Om1[16];
            #pragma unroll
            for(int r=0;r<16;r++){ Om0[r]=0.f; Om1[r]=0.f; }
            float mst = -1e30f;
            #pragma unroll
            for(int sl=0; sl<4; sl++)
                if (qid[sl] == wv) mst = fmaxf(mst, Msh[sl*32 + l31]);
            float lst = 0.f;
            #pragma unroll
            for(int sl=0; sl<4; sl++){
                if (qid[sl] == wv){
                    float c = fexp2(Msh[sl*32 + l31] - mst);
                    lst += c * Lsh[sl*32 + l31];
                    const float* Ob = Osh + sl*2048;
                    #pragma unroll
                    for(int r=0;r<16;r++){
                        int d0 = (r&3) + 8*(r>>2) + 4*hi;
                        Om0[r] += c * Ob[d0*32 + l31];
                        Om1[r] += c * Ob[(d0+32)*32 + l31];
                    }
                }
            }
            float invl = 1.0f / lst;
            int j = (wv == 0) ? jB : jA;
            int q = j*32 + l31;
            size_t obase = (size_t)(b*TT + q)*DIM + (bh & 15)*HD + 4*hi;
            #pragma unroll
            for(int u=0;u<4;u++){
                float4 o0, o1;
                o0.x=Om0[4*u+0]*invl; o0.y=Om0[4*u+1]*invl; o0.z=Om0[4*u+2]*invl; o0.w=Om0[4*u+3]*invl;
                o1.x=Om1[4*u+0]*invl; o1.y=Om1[4*u+1]*invl; o1.z=Om1[4*u+2]*invl; o1.w=Om1[4*u+3]*invl;
                *(float4*)(ao + obase + 8*u)      = o0;
                *(float4*)(ao + obase + 32 + 8*u) = o1;
            }
        }
    }
}

// ---------------- launch ----------------
extern "C" void kernel_launch(void* const* d_in, const int* in_sizes, int n_in,
                              void* d_out, int out_size, void* d_ws, size_t ws_size,
                              hipStream_t stream){
    const float* x    = (const float*)d_in[0];
    const float* cosb = (const float*)d_in[1];
    const float* sinb = (const float*)d_in[2];
    const float* wq_w = (const float*)d_in[3];
    const float* wk_w = (const float*)d_in[4];
    const float* wv_w = (const float*)d_in[5];
    const float* wo_w = (const float*)d_in[6];
    float* out = (float*)d_out;

    char* cw = (char*)d_ws;
    const size_t MB = 1048576;
    char*  wpk   = cw;                             // [0,4MB) fragment-order weights
    float* wsall = (float*)(cw + 4*MB);            // 128 KB
    float* srow1 = (float*)(cw + 4*MB + 131072);   // 16 KB
    float* srow2 = (float*)(cw + 4*MB + 147456);   // 16 KB
    char*  xpk   = cw + 5*MB;                      // [5,9MB)  fragment-order activations
    char*  xpk2  = cw + 9*MB;                      // [9,13MB)
    unsigned short* Qh = (unsigned short*)(cw + 13*MB);  // [13,21MB) Q row-major
    unsigned short* Kf = (unsigned short*)(cw + 21*MB);  // [21,29MB) K frag-order
    unsigned short* Vf = (unsigned short*)(cw + 29*MB);  // [29,37MB) V^T frag-order
    float* ao    = (float*)(cw + 37*MB);           // [37,53MB)

    quant_all<<<1024 + MROWS, 256, 0, stream>>>(x, wq_w, wk_w, wv_w, wo_w,
                                                wpk, wsall, xpk, srow1);

    gemm_qkv<<<dim3(24, MROWS/64), 128, 0, stream>>>(xpk, wpk, wsall, srow1,
                                                     cosb, sinb, Qh, Kf, Vf);

    attn_mfma9<<<1024, 256, 0, stream>>>(Qh, Kf, Vf, ao);

    quant_x_i8<<<MROWS, 256, 0, stream>>>(ao, xpk2, srow2);
    gemm_i8<<<dim3(DIM/128, MROWS/64), 256, 0, stream>>>(xpk2, wpk + 3*MB,
                                                         wsall + 3*8192, srow2, out);
}